// Round 3
// baseline (926.618 us; speedup 1.0000x reference)
//
#include <hip/hip_runtime.h>
#include <stdint.h>

#define NROWS 65536
#define IDIM 2048

typedef __attribute__((ext_vector_type(4))) float v4f;
typedef __attribute__((ext_vector_type(8))) short v8s;

__device__ __forceinline__ unsigned short f2bf(float f) {
  unsigned int u = __float_as_uint(f);
  u += 0x7fffu + ((u >> 16) & 1u);          // round-to-nearest-even
  return (unsigned short)(u >> 16);
}
__device__ __forceinline__ float bf2f(unsigned short h) {
  return __uint_as_float(((unsigned int)h) << 16);
}
__device__ __forceinline__ v8s pack8(v4f u, v4f v) {
  v8s r;
  r[0] = (short)f2bf(u[0]); r[1] = (short)f2bf(u[1]);
  r[2] = (short)f2bf(u[2]); r[3] = (short)f2bf(u[3]);
  r[4] = (short)f2bf(v[0]); r[5] = (short)f2bf(v[1]);
  r[6] = (short)f2bf(v[2]); r[7] = (short)f2bf(v[3]);
  return r;
}

struct Expert {
  const unsigned short* w1t;   // [HN][2048] bf16
  const float* b1;
  const unsigned short* w2t;   // [HN/2][HN] bf16
  const float* b2;
  const float* w3;             // [HN/2]
  const float* b3;             // [1]
  const int* idx;              // this expert's row-index list
  const int* count;
};
struct Quad { Expert e[4]; };

// ---------------- prep kernel 1: bucket rows by label ----------------
__global__ void build_lists(const int* __restrict__ labels, float* __restrict__ out,
                            int* __restrict__ counts, int* __restrict__ idx, int n)
{
  __shared__ int lcnt[4];
  __shared__ int lbase[4];
  const int t = threadIdx.x;
  if (t < 4) lcnt[t] = 0;
  __syncthreads();
  const int i = blockIdx.x * blockDim.x + t;
  int lbl = -1, pos = 0;
  if (i < n) {
    lbl = labels[i];
    if (lbl >= 0 && lbl <= 3) {
      pos = atomicAdd(&lcnt[lbl], 1);
    } else {
      out[i] = 0.f;   // rows with unknown label output 0 (d_out is poisoned)
      lbl = -1;
    }
  }
  __syncthreads();
  if (t < 4) lbase[t] = atomicAdd(&counts[t], lcnt[t]);
  __syncthreads();
  if (lbl >= 0) idx[lbl * NROWS + lbase[lbl] + pos] = i;
}

// ---------------- prep kernel 2: transpose + fp32->bf16 weights (all 4 experts) ----------------
struct ConvE { const float* W1; const float* W2; unsigned short* w1t; unsigned short* w2t; int HN; int total; };
struct Conv4 { ConvE c[4]; };

__global__ void conv_all(Conv4 q)
{
  const ConvE c = q.c[blockIdx.y];
  const int i = blockIdx.x * blockDim.x + threadIdx.x;
  if (i >= c.total) return;
  const int n1 = IDIM * c.HN;
  const int HN2 = c.HN >> 1;
  if (i < n1) {
    int nn = i / IDIM, k = i - nn * IDIM;
    c.w1t[i] = f2bf(c.W1[k * c.HN + nn]);        // w1t[n][k] = W1[k][n]
  } else {
    int j = i - n1;
    int nn = j / c.HN, k = j - nn * c.HN;
    c.w2t[j] = f2bf(c.W2[k * HN2 + nn]);         // w2t[n][k] = W2[k][n]
  }
}

// ---------------- main fused kernel: barrier-free, per-wave independent ----------------
// Each wave owns 32 rows of its expert's gathered list. A-fragments load
// straight from global x (fp32 -> bf16 in reg); B-fragments straight from the
// pre-transposed bf16 weights (L2-hot). h1/h2 round-trip through a PRIVATE
// per-wave LDS region -> no __syncthreads anywhere.
// LDS: 4 waves x 32 x 136 bf16 = 34816 B. launch_bounds(256,3) -> 12 waves/CU.
#define WREG (32 * 136)   // per-wave LDS region, bf16 elements (max across HN)

template<int HN>
__device__ __forceinline__ void moe_body(const float* __restrict__ x, float* __restrict__ out,
                                         const Expert E, unsigned short* smem)
{
  constexpr int HN2 = HN / 2;
  constexpr int TM = 128, BK = 32;
  constexpr int NF1 = HN / 16;
  constexpr int NF2 = HN2 / 16;
  constexpr int H1W = HN + 8;
  constexpr int H2W = HN2 + 4;

  const int cnt = *E.count;
  const int tile0 = blockIdx.x * TM;
  if (tile0 >= cnt) return;
  const int rv = min(TM, cnt - tile0);

  const int t    = threadIdx.x;
  const int lane = t & 63;
  const int wid  = t >> 6;
  const int l15  = lane & 15;
  const int quad = lane >> 4;
  const int m0w  = wid * 32;          // wave's first tile-row

  unsigned short* sH1 = smem + wid * WREG;   // [32][H1W] per-wave private
  unsigned short* sH2 = sH1;                 // [32][H2W] aliases (h1 consumed first)

  // row ids for this lane's two A-fragments (clamp tail to a valid row)
  const int r0 = min(m0w + l15,      rv - 1);
  const int r1 = min(m0w + 16 + l15, rv - 1);
  const int rid0 = E.idx[tile0 + r0];
  const int rid1 = E.idx[tile0 + r1];
  const float* pa0 = x + (size_t)rid0 * IDIM + quad * 8;
  const float* pa1 = x + (size_t)rid1 * IDIM + quad * 8;
  const unsigned short* pb = E.w1t + (size_t)l15 * IDIM + quad * 8;

  // ---- layer 1: K-loop over IDIM, no barriers ----
  v4f acc[2][NF1];
  #pragma unroll
  for (int mi = 0; mi < 2; ++mi)
    #pragma unroll
    for (int ni = 0; ni < NF1; ++ni)
      acc[mi][ni] = (v4f){0.f, 0.f, 0.f, 0.f};

  for (int k0 = 0; k0 < IDIM; k0 += BK) {
    v4f u0 = *(const v4f*)(pa0 + k0);
    v4f v0 = *(const v4f*)(pa0 + k0 + 4);
    v4f u1 = *(const v4f*)(pa1 + k0);
    v4f v1 = *(const v4f*)(pa1 + k0 + 4);
    v8s a0 = pack8(u0, v0);
    v8s a1 = pack8(u1, v1);
    #pragma unroll
    for (int ni = 0; ni < NF1; ++ni) {
      v8s b = *(const v8s*)(pb + (size_t)ni * 16 * IDIM + k0);
      acc[0][ni] = __builtin_amdgcn_mfma_f32_16x16x32_bf16(a0, b, acc[0][ni], 0, 0, 0);
      acc[1][ni] = __builtin_amdgcn_mfma_f32_16x16x32_bf16(a1, b, acc[1][ni], 0, 0, 0);
    }
  }

  // ---- epilogue 1: h1 = relu(acc + b1) -> per-wave LDS, bf16 ----
  #pragma unroll
  for (int mi = 0; mi < 2; ++mi) {
    #pragma unroll
    for (int ni = 0; ni < NF1; ++ni) {
      const int col = ni * 16 + l15;
      const float b1v = E.b1[col];
      #pragma unroll
      for (int r = 0; r < 4; ++r) {
        const int lr = mi * 16 + quad * 4 + r;
        sH1[lr * H1W + col] = f2bf(fmaxf(acc[mi][ni][r] + b1v, 0.f));
      }
    }
  }

  // ---- layer 2: K = HN, A from LDS h1, B straight from global (L2-hot) ----
  v4f acc2[2][NF2];
  #pragma unroll
  for (int mi = 0; mi < 2; ++mi)
    #pragma unroll
    for (int ni = 0; ni < NF2; ++ni)
      acc2[mi][ni] = (v4f){0.f, 0.f, 0.f, 0.f};
  const unsigned short* pb2 = E.w2t + (size_t)l15 * HN + quad * 8;
  #pragma unroll
  for (int ks = 0; ks < HN; ks += 32) {
    v8s a20 = *(const v8s*)&sH1[(l15)      * H1W + ks + quad * 8];
    v8s a21 = *(const v8s*)&sH1[(16 + l15) * H1W + ks + quad * 8];
    #pragma unroll
    for (int ni = 0; ni < NF2; ++ni) {
      v8s b = *(const v8s*)(pb2 + (size_t)ni * 16 * HN + ks);
      acc2[0][ni] = __builtin_amdgcn_mfma_f32_16x16x32_bf16(a20, b, acc2[0][ni], 0, 0, 0);
      acc2[1][ni] = __builtin_amdgcn_mfma_f32_16x16x32_bf16(a21, b, acc2[1][ni], 0, 0, 0);
    }
  }

  // ---- epilogue 2: h2 = relu(acc2 + b2) -> same LDS region (h1 is dead) ----
  #pragma unroll
  for (int mi = 0; mi < 2; ++mi) {
    #pragma unroll
    for (int ni = 0; ni < NF2; ++ni) {
      const int col = ni * 16 + l15;
      const float b2v = E.b2[col];
      #pragma unroll
      for (int r = 0; r < 4; ++r) {
        const int lr = mi * 16 + quad * 4 + r;
        sH2[lr * H2W + col] = f2bf(fmaxf(acc2[mi][ni][r] + b2v, 0.f));
      }
    }
  }

  // ---- layer 3: per-row dot of length HN/2 (lanes 0..31, one row each) ----
  if (lane < 32) {
    const int gr = m0w + lane;
    if (gr < rv) {
      float a3 = E.b3[0];
      #pragma unroll
      for (int j = 0; j < HN2; ++j)
        a3 = fmaf(bf2f(sH2[lane * H2W + j]), E.w3[j], a3);
      out[E.idx[tile0 + gr]] = a3;
    }
  }
}

__global__ __launch_bounds__(256, 3)
void moe_main(const float* __restrict__ x, float* __restrict__ out, Quad q)
{
  __shared__ __align__(16) unsigned short smem[4 * WREG];
  const int e = blockIdx.y;
  if (e < 2) moe_body<64>(x, out, q.e[e], smem);
  else       moe_body<128>(x, out, q.e[e], smem);
}

// ---------------- host ----------------
extern "C" void kernel_launch(void* const* d_in, const int* in_sizes, int n_in,
                              void* d_out, int out_size, void* d_ws, size_t ws_size,
                              hipStream_t stream)
{
  const float* x   = (const float*)d_in[0];
  const int* labels = (const int*)d_in[1];
  float* out = (float*)d_out;

  char* ws = (char*)d_ws;
  int* counts = (int*)ws;                       // 16 B
  int* idx = (int*)(ws + 256);                  // 4 * 65536 ints = 1 MiB
  static const int HNs[4] = {64, 64, 128, 128};
  unsigned short* w1t[4];
  unsigned short* w2t[4];
  size_t off = 256 + (size_t)4 * NROWS * 4;
  for (int e = 0; e < 4; ++e) { w1t[e] = (unsigned short*)(ws + off); off += (size_t)IDIM * HNs[e] * 2; }
  for (int e = 0; e < 4; ++e) { w2t[e] = (unsigned short*)(ws + off); off += (size_t)HNs[e] * (HNs[e] / 2) * 2; }

  hipMemsetAsync(counts, 0, 4 * sizeof(int), stream);
  build_lists<<<dim3(NROWS / 256), dim3(256), 0, stream>>>(labels, out, counts, idx, NROWS);

  Conv4 cq;
  int maxtotal = 0;
  for (int e = 0; e < 4; ++e) {
    const int total = IDIM * HNs[e] + HNs[e] * (HNs[e] / 2);
    cq.c[e].W1 = (const float*)d_in[2 + 6 * e + 0];
    cq.c[e].W2 = (const float*)d_in[2 + 6 * e + 2];
    cq.c[e].w1t = w1t[e];
    cq.c[e].w2t = w2t[e];
    cq.c[e].HN = HNs[e];
    cq.c[e].total = total;
    if (total > maxtotal) maxtotal = total;
  }
  conv_all<<<dim3((maxtotal + 255) / 256, 4), dim3(256), 0, stream>>>(cq);

  Quad q;
  for (int e = 0; e < 4; ++e) {
    q.e[e].w1t = w1t[e];
    q.e[e].b1  = (const float*)d_in[2 + 6 * e + 1];
    q.e[e].w2t = w2t[e];
    q.e[e].b2  = (const float*)d_in[2 + 6 * e + 3];
    q.e[e].w3  = (const float*)d_in[2 + 6 * e + 4];
    q.e[e].b3  = (const float*)d_in[2 + 6 * e + 5];
    q.e[e].idx = idx + (size_t)e * NROWS;
    q.e[e].count = counts + e;
  }
  moe_main<<<dim3(NROWS / 128, 4), dim3(256), 0, stream>>>(x, out, q);
}